// Round 2
// baseline (876.472 us; speedup 1.0000x reference)
//
#include <hip/hip_runtime.h>

#define D 128
#define R_REL 10
#define NBASE 4
#define NC 12
#define LN_EPS 1e-5f

// ---------------- utility: copy fallback -> x ----------------
__global__ void k_copy(const float4* __restrict__ src, float4* __restrict__ dst, int n4) {
    int i = blockIdx.x * blockDim.x + threadIdx.x;
    if (i < n4) dst[i] = src[i];
}

// ---------------- typed projection: x[idx[m]] = feats[m] @ W + b ----------------
// 128 threads/block, 8 rows per block. K <= 256.
__global__ void k_proj8(const float* __restrict__ feats, const float* __restrict__ W,
                        const float* __restrict__ bias, const int* __restrict__ idx,
                        float* __restrict__ x, int M, int K) {
    __shared__ float lds[8 * 256];
    int m0 = blockIdx.x * 8;
    int rows = M - m0; if (rows > 8) rows = 8;
    for (int i = threadIdx.x; i < rows * K; i += 128) {
        int r = i / K, k = i - r * K;
        lds[r * K + k] = feats[(size_t)(m0 + r) * K + k];
    }
    __syncthreads();
    int o = threadIdx.x;  // 0..127 output col
    float bz = bias[o];
    float acc[8];
#pragma unroll
    for (int r = 0; r < 8; ++r) acc[r] = bz;
    for (int k = 0; k < K; ++k) {
        float wv = W[k * D + o];
#pragma unroll
        for (int r = 0; r < 8; ++r) acc[r] = fmaf(lds[r * K + k], wv, acc[r]);
    }
#pragma unroll
    for (int r = 0; r < 8; ++r) {
        if (r < rows) x[(size_t)idx[m0 + r] * D + o] = acc[r];
    }
}

// ---------------- degree histogram ----------------
__global__ void k_deg(const int* __restrict__ ei, int* __restrict__ deg, int E) {
    int e = blockIdx.x * blockDim.x + threadIdx.x;
    if (e < E) atomicAdd(&deg[ei[E + e]], 1);
}

// ---------------- exclusive scan (3 kernels), N <= 256*256 ----------------
#define SCAN_B 256
__global__ void k_scan1(const int* __restrict__ deg, int* __restrict__ off,
                        int* __restrict__ bsum, int n) {
    __shared__ int lds[SCAN_B];
    int i = blockIdx.x * SCAN_B + threadIdx.x;
    int v = (i < n) ? deg[i] : 0;
    lds[threadIdx.x] = v; __syncthreads();
    for (int s = 1; s < SCAN_B; s <<= 1) {
        int t = (threadIdx.x >= s) ? lds[threadIdx.x - s] : 0;
        __syncthreads();
        lds[threadIdx.x] += t;
        __syncthreads();
    }
    if (i < n) off[i] = lds[threadIdx.x] - v;  // exclusive
    if (threadIdx.x == SCAN_B - 1) bsum[blockIdx.x] = lds[threadIdx.x];
}
__global__ void k_scan2(int* __restrict__ bsum, int nb) {
    __shared__ int lds[SCAN_B];
    int v = (threadIdx.x < nb) ? bsum[threadIdx.x] : 0;
    lds[threadIdx.x] = v; __syncthreads();
    for (int s = 1; s < SCAN_B; s <<= 1) {
        int t = (threadIdx.x >= s) ? lds[threadIdx.x - s] : 0;
        __syncthreads();
        lds[threadIdx.x] += t;
        __syncthreads();
    }
    if (threadIdx.x < nb) bsum[threadIdx.x] = lds[threadIdx.x] - v;  // exclusive over blocks
}
__global__ void k_scan3(int* __restrict__ off, const int* __restrict__ bsum,
                        int* __restrict__ cursor, int n) {
    int i = blockIdx.x * SCAN_B + threadIdx.x;
    if (i < n) {
        int o = off[i] + bsum[blockIdx.x];
        off[i] = o;
        cursor[i] = o;
    }
}

// ---------------- CSR fill: csr[p] = src | etype<<16 ----------------
__global__ void k_fill(const int* __restrict__ ei, const int* __restrict__ et,
                       int* __restrict__ cursor, unsigned* __restrict__ csr, int E) {
    int e = blockIdx.x * blockDim.x + threadIdx.x;
    if (e < E) {
        int d = ei[E + e];
        int p = atomicAdd(&cursor[d], 1);
        csr[p] = (unsigned)ei[e] | ((unsigned)et[e] << 16);
    }
}

// ---------------- aggregation over node range [n0, n0+cnt):
// Z[nl, b*128+d] = sum_r comp[r,b] * mean[r, n0+nl, d]   (nl = local row)
// 256 threads = 4 waves, one node per wave. LDS per-relation accumulators.
// off/deg passed pre-offset by n0; Z is chunk-local.
__global__ void k_agg(const float* __restrict__ xin, const int* __restrict__ off,
                      const int* __restrict__ deg, const unsigned* __restrict__ csr,
                      const float* __restrict__ comp, float* __restrict__ Z, int cnt) {
    __shared__ float acc[4][R_REL][D];   // 20 KB
    __shared__ float scomp[R_REL * NBASE];
    int w = threadIdx.x >> 6;
    int lane = threadIdx.x & 63;
    if (threadIdx.x < R_REL * NBASE) scomp[threadIdx.x] = comp[threadIdx.x];
    for (int i = threadIdx.x; i < 4 * R_REL * D; i += 256) ((float*)acc)[i] = 0.f;
    __syncthreads();

    int n = blockIdx.x * 4 + w;   // local node index within chunk
    if (n >= cnt) return;

    int start = off[n];
    int dg = deg[n];
    int myCnt = 0;  // lane r holds count of relation r (for r < R_REL)
    float* accw = &acc[w][0][0];
    for (int j = 0; j < dg; ++j) {
        unsigned u = csr[start + j];
        int src = (int)(u & 0xFFFFu);
        int et = (int)(u >> 16);
        float2 v = *(const float2*)&xin[(size_t)src * D + lane * 2];
        float2 a = *(float2*)&accw[et * D + lane * 2];
        a.x += v.x; a.y += v.y;
        *(float2*)&accw[et * D + lane * 2] = a;
        if (lane == et) myCnt++;
    }
    float inv[R_REL];
#pragma unroll
    for (int r = 0; r < R_REL; ++r) {
        int c = __shfl(myCnt, r, 64);
        inv[r] = (c > 0) ? (1.f / (float)c) : 1.f;   // max(cnt,1)
    }
    float2 mean[R_REL];
#pragma unroll
    for (int r = 0; r < R_REL; ++r) {
        float2 a = *(float2*)&accw[r * D + lane * 2];
        mean[r].x = a.x * inv[r];
        mean[r].y = a.y * inv[r];
    }
#pragma unroll
    for (int b = 0; b < NBASE; ++b) {
        float2 zz = make_float2(0.f, 0.f);
#pragma unroll
        for (int r = 0; r < R_REL; ++r) {
            float c = scomp[r * NBASE + b];
            zz.x = fmaf(c, mean[r].x, zz.x);
            zz.y = fmaf(c, mean[r].y, zz.y);
        }
        *(float2*)&Z[(size_t)n * 512 + b * D + lane * 2] = zz;
    }
}

// ---------------- fused layer GEMM over chunk rows:
// P[m] = [Z[m] | xin[m]] @ [bases; root] + bias    (m local to chunk)
// M=cnt, K=640, N=128. BM=64, BN=128, BK=32, 256 threads, 8x4 per thread.
// xin and P passed pre-offset by n0*D.
__global__ void k_gemm(const float* __restrict__ Z, const float* __restrict__ xin,
                       const float* __restrict__ bases, const float* __restrict__ root,
                       const float* __restrict__ bias, float* __restrict__ P, int cnt) {
    __shared__ float As[64][33];
    __shared__ float Bs[32][128];
    int tx = threadIdx.x & 31;
    int ty = threadIdx.x >> 5;
    int m0 = blockIdx.x * 64;
    float acc[8][4] = {};

    for (int k0 = 0; k0 < 640; k0 += 32) {
        // A tile: 64 rows x 32 cols; 2 float4 per thread
#pragma unroll
        for (int i = 0; i < 2; ++i) {
            int q = threadIdx.x * 2 + i;       // 0..511
            int row = q >> 3;                  // 0..63
            int col = (q & 7) * 4;             // 0..28
            int mrow = m0 + row;
            float4 v = make_float4(0.f, 0.f, 0.f, 0.f);
            if (mrow < cnt) {
                if (k0 < 512) v = *(const float4*)&Z[(size_t)mrow * 512 + k0 + col];
                else          v = *(const float4*)&xin[(size_t)mrow * D + (k0 - 512) + col];
            }
            As[row][col] = v.x; As[row][col + 1] = v.y;
            As[row][col + 2] = v.z; As[row][col + 3] = v.w;
        }
        // B tile: 32 k-rows x 128 cols; 4 float4 per thread
#pragma unroll
        for (int i = 0; i < 4; ++i) {
            int q = threadIdx.x * 4 + i;       // 0..1023
            int kr = q >> 5;                   // 0..31
            int c4 = (q & 31) * 4;             // 0..124
            int kg = k0 + kr;
            const float* src = (kg < 512) ? &bases[(size_t)kg * D + c4]
                                          : &root[(size_t)(kg - 512) * D + c4];
            *(float4*)&Bs[kr][c4] = *(const float4*)src;
        }
        __syncthreads();
#pragma unroll
        for (int kk = 0; kk < 32; ++kk) {
            float b[4];
            *(float4*)b = *(const float4*)&Bs[kk][tx * 4];
#pragma unroll
            for (int i = 0; i < 8; ++i) {
                float a = As[ty + i * 8][kk];
                acc[i][0] = fmaf(a, b[0], acc[i][0]);
                acc[i][1] = fmaf(a, b[1], acc[i][1]);
                acc[i][2] = fmaf(a, b[2], acc[i][2]);
                acc[i][3] = fmaf(a, b[3], acc[i][3]);
            }
        }
        __syncthreads();
    }
    float4 bv = *(const float4*)&bias[tx * 4];
#pragma unroll
    for (int i = 0; i < 8; ++i) {
        int m = m0 + ty + i * 8;
        if (m < cnt) {
            float4 o;
            o.x = acc[i][0] + bv.x; o.y = acc[i][1] + bv.y;
            o.z = acc[i][2] + bv.z; o.w = acc[i][3] + bv.w;
            *(float4*)&P[(size_t)m * D + tx * 4] = o;
        }
    }
}

// ---------------- LayerNorm + ReLU over rows ----------------
__global__ void k_lnrelu(const float* __restrict__ P, const float* __restrict__ g,
                         const float* __restrict__ b, float* __restrict__ h, int Nn) {
    int w = threadIdx.x >> 6, lane = threadIdx.x & 63;
    int n = blockIdx.x * 4 + w;
    if (n >= Nn) return;
    float2 v = *(const float2*)&P[(size_t)n * D + lane * 2];
    float s = v.x + v.y;
#pragma unroll
    for (int o = 1; o < 64; o <<= 1) s += __shfl_xor(s, o, 64);
    float m = s * (1.f / 128.f);
    float dx = v.x - m, dy = v.y - m;
    float vs = dx * dx + dy * dy;
#pragma unroll
    for (int o = 1; o < 64; o <<= 1) vs += __shfl_xor(vs, o, 64);
    float inv = rsqrtf(vs * (1.f / 128.f) + LN_EPS);
    float2 gg = *(const float2*)&g[lane * 2];
    float2 bb = *(const float2*)&b[lane * 2];
    float2 o2;
    o2.x = fmaxf(dx * inv * gg.x + bb.x, 0.f);
    o2.y = fmaxf(dy * inv * gg.y + bb.y, 0.f);
    *(float2*)&h[(size_t)n * D + lane * 2] = o2;
}

// ---------------- final: gather + LN + relu(h@Wc1+bc1) @ Wc2 + bc2 ----------------
__global__ void k_final(const float* __restrict__ P2, const int* __restrict__ nidx,
                        const float* __restrict__ g, const float* __restrict__ b,
                        const float* __restrict__ Wc1, const float* __restrict__ bc1,
                        const float* __restrict__ Wc2, const float* __restrict__ bc2,
                        float* __restrict__ out, int M) {
    __shared__ float ln[D];
    __shared__ float t[D];
    __shared__ float red[2];
    int i = blockIdx.x;
    if (i >= M) return;
    int d = threadIdx.x;
    int n = nidx[i];
    float v = P2[(size_t)n * D + d];
    float s = v;
#pragma unroll
    for (int o = 1; o < 64; o <<= 1) s += __shfl_xor(s, o, 64);
    if ((d & 63) == 0) red[d >> 6] = s;
    __syncthreads();
    float m = (red[0] + red[1]) * (1.f / 128.f);
    __syncthreads();
    float dv = v - m;
    float vs = dv * dv;
#pragma unroll
    for (int o = 1; o < 64; o <<= 1) vs += __shfl_xor(vs, o, 64);
    if ((d & 63) == 0) red[d >> 6] = vs;
    __syncthreads();
    float inv = rsqrtf((red[0] + red[1]) * (1.f / 128.f) + LN_EPS);
    ln[d] = dv * inv * g[d] + b[d];
    __syncthreads();
    float a = bc1[d];
    for (int k = 0; k < D; ++k) a = fmaf(ln[k], Wc1[k * D + d], a);
    t[d] = fmaxf(a, 0.f);
    __syncthreads();
    if (d < NC) {
        float o2 = bc2[d];
        for (int k = 0; k < D; ++k) o2 = fmaf(t[k], Wc2[k * NC + d], o2);
        out[(size_t)i * NC + d] = o2;
    }
}

extern "C" void kernel_launch(void* const* d_in, const int* in_sizes, int n_in,
                              void* d_out, int out_size, void* d_ws, size_t ws_size,
                              hipStream_t stream) {
    const int*   edge_index   = (const int*)d_in[0];
    const int*   edge_type    = (const int*)d_in[1];
    const int*   node_indices = (const int*)d_in[2];
    const float* file_feats   = (const float*)d_in[3];
    const int*   file_idx     = (const int*)d_in[4];
    const float* domain_feats = (const float*)d_in[5];
    const int*   domain_idx   = (const int*)d_in[6];
    const float* ip_feats     = (const float*)d_in[7];
    const int*   ip_idx       = (const int*)d_in[8];
    const float* fallback     = (const float*)d_in[9];
    const float* Wf = (const float*)d_in[10]; const float* bf = (const float*)d_in[11];
    const float* Wd = (const float*)d_in[12]; const float* bd = (const float*)d_in[13];
    const float* Wi = (const float*)d_in[14]; const float* bi = (const float*)d_in[15];
    const float* comp1 = (const float*)d_in[16]; const float* bases1 = (const float*)d_in[17];
    const float* root1 = (const float*)d_in[18]; const float* bias1 = (const float*)d_in[19];
    const float* comp2 = (const float*)d_in[20]; const float* bases2 = (const float*)d_in[21];
    const float* root2 = (const float*)d_in[22]; const float* bias2 = (const float*)d_in[23];
    const float* ln1g = (const float*)d_in[24]; const float* ln1b = (const float*)d_in[25];
    const float* ln2g = (const float*)d_in[26]; const float* ln2b = (const float*)d_in[27];
    const float* Wc1 = (const float*)d_in[28]; const float* bc1 = (const float*)d_in[29];
    const float* Wc2 = (const float*)d_in[30]; const float* bc2 = (const float*)d_in[31];

    const int E  = in_sizes[1];
    const int Nn = in_sizes[9] / D;
    const int Mf = in_sizes[4], Kf = in_sizes[3] / Mf;
    const int Md = in_sizes[6], Kd = in_sizes[5] / Md;
    const int Mi = in_sizes[8], Ki = in_sizes[7] / Mi;
    const int Msel = in_sizes[2];

    // chunking of the agg->gemm pipeline (caps Z to CH rows)
    const int CH = ((Nn / 2 + 63) / 64) * 64;   // ~25024 for Nn=50000

    char* w = (char*)d_ws;
    auto alloc = [&](size_t bytes) {
        char* p = w;
        w += (bytes + 255) & ~(size_t)255;
        return p;
    };
    float* x  = (float*)alloc((size_t)Nn * D * 4);
    float* h1 = (float*)alloc((size_t)Nn * D * 4);
    float* P  = (float*)alloc((size_t)Nn * D * 4);
    float* Z  = (float*)alloc((size_t)CH * 512 * 4);
    int* deg    = (int*)alloc((size_t)Nn * 4);
    int* off    = (int*)alloc((size_t)Nn * 4);
    int* cursor = (int*)alloc((size_t)Nn * 4);
    int* bsum   = (int*)alloc(1024);
    unsigned* csr = (unsigned*)alloc((size_t)E * 4);

    hipMemsetAsync(deg, 0, (size_t)Nn * 4, stream);

    // build node features
    int n4 = Nn * D / 4;
    k_copy<<<(n4 + 255) / 256, 256, 0, stream>>>((const float4*)fallback, (float4*)x, n4);
    k_proj8<<<(Mf + 7) / 8, 128, 0, stream>>>(file_feats, Wf, bf, file_idx, x, Mf, Kf);
    k_proj8<<<(Md + 7) / 8, 128, 0, stream>>>(domain_feats, Wd, bd, domain_idx, x, Md, Kd);
    k_proj8<<<(Mi + 7) / 8, 128, 0, stream>>>(ip_feats, Wi, bi, ip_idx, x, Mi, Ki);

    // build CSR by dst (shared by both layers)
    k_deg<<<(E + 255) / 256, 256, 0, stream>>>(edge_index, deg, E);
    int nb = (Nn + SCAN_B - 1) / SCAN_B;
    k_scan1<<<nb, SCAN_B, 0, stream>>>(deg, off, bsum, Nn);
    k_scan2<<<1, SCAN_B, 0, stream>>>(bsum, nb);
    k_scan3<<<nb, SCAN_B, 0, stream>>>(off, bsum, cursor, Nn);
    k_fill<<<(E + 255) / 256, 256, 0, stream>>>(edge_index, edge_type, cursor, csr, E);

    // layer 1 (chunked over node ranges)
    for (int n0 = 0; n0 < Nn; n0 += CH) {
        int cnt = Nn - n0; if (cnt > CH) cnt = CH;
        k_agg<<<(cnt + 3) / 4, 256, 0, stream>>>(x, off + n0, deg + n0, csr, comp1, Z, cnt);
        k_gemm<<<(cnt + 63) / 64, 256, 0, stream>>>(Z, x + (size_t)n0 * D, bases1, root1,
                                                    bias1, P + (size_t)n0 * D, cnt);
    }
    k_lnrelu<<<(Nn + 3) / 4, 256, 0, stream>>>(P, ln1g, ln1b, h1, Nn);

    // layer 2
    for (int n0 = 0; n0 < Nn; n0 += CH) {
        int cnt = Nn - n0; if (cnt > CH) cnt = CH;
        k_agg<<<(cnt + 3) / 4, 256, 0, stream>>>(h1, off + n0, deg + n0, csr, comp2, Z, cnt);
        k_gemm<<<(cnt + 63) / 64, 256, 0, stream>>>(Z, h1 + (size_t)n0 * D, bases2, root2,
                                                    bias2, P + (size_t)n0 * D, cnt);
    }

    // head: gather + LN2 + MLP
    k_final<<<Msel, 128, 0, stream>>>(P, node_indices, ln2g, ln2b, Wc1, bc1, Wc2, bc2,
                                      (float*)d_out, Msel);
}

// Round 5
// 543.741 us; speedup vs baseline: 1.6119x; 1.6119x over previous
//
#include <hip/hip_runtime.h>

#define D 128
#define R_REL 10
#define NBASE 4
#define NC 12
#define LN_EPS 1e-5f

typedef __attribute__((ext_vector_type(8))) short short8;
typedef __attribute__((ext_vector_type(4))) float f32x4;

static __device__ __forceinline__ unsigned short f2bf(float f) {
    unsigned u = __float_as_uint(f);
    unsigned r = (u + 0x7FFFu + ((u >> 16) & 1u)) >> 16;   // RNE
    return (unsigned short)r;
}

// ---------------- fallback f32 -> xb bf16 ----------------
__global__ void k_copy_bf(const float4* __restrict__ src, uint2* __restrict__ dst, int n4) {
    int i = blockIdx.x * blockDim.x + threadIdx.x;
    if (i < n4) {
        float4 v = src[i];
        uint2 o;
        o.x = (unsigned)f2bf(v.x) | ((unsigned)f2bf(v.y) << 16);
        o.y = (unsigned)f2bf(v.z) | ((unsigned)f2bf(v.w) << 16);
        dst[i] = o;
    }
}

// ---------------- typed projection: xb[idx[m]] = bf16(feats[m] @ W + b) ----------------
__global__ void k_proj8(const float* __restrict__ feats, const float* __restrict__ W,
                        const float* __restrict__ bias, const int* __restrict__ idx,
                        unsigned short* __restrict__ xb, int M, int K) {
    __shared__ float lds[8 * 256];
    int m0 = blockIdx.x * 8;
    int rows = M - m0; if (rows > 8) rows = 8;
    for (int i = threadIdx.x; i < rows * K; i += 128) {
        int r = i / K, k = i - r * K;
        lds[r * K + k] = feats[(size_t)(m0 + r) * K + k];
    }
    __syncthreads();
    int o = threadIdx.x;  // 0..127 output col
    float bz = bias[o];
    float acc[8];
#pragma unroll
    for (int r = 0; r < 8; ++r) acc[r] = bz;
    for (int k = 0; k < K; ++k) {
        float wv = W[k * D + o];
#pragma unroll
        for (int r = 0; r < 8; ++r) acc[r] = fmaf(lds[r * K + k], wv, acc[r]);
    }
#pragma unroll
    for (int r = 0; r < 8; ++r) {
        if (r < rows) xb[(size_t)idx[m0 + r] * D + o] = f2bf(acc[r]);
    }
}

// ---------------- degree histogram ----------------
__global__ void k_deg(const int* __restrict__ ei, int* __restrict__ deg, int E) {
    int e = blockIdx.x * blockDim.x + threadIdx.x;
    if (e < E) atomicAdd(&deg[ei[E + e]], 1);
}

// ---------------- exclusive scan (3 kernels) ----------------
#define SCAN_B 256
__global__ void k_scan1(const int* __restrict__ deg, int* __restrict__ off,
                        int* __restrict__ bsum, int n) {
    __shared__ int lds[SCAN_B];
    int i = blockIdx.x * SCAN_B + threadIdx.x;
    int v = (i < n) ? deg[i] : 0;
    lds[threadIdx.x] = v; __syncthreads();
    for (int s = 1; s < SCAN_B; s <<= 1) {
        int t = (threadIdx.x >= s) ? lds[threadIdx.x - s] : 0;
        __syncthreads();
        lds[threadIdx.x] += t;
        __syncthreads();
    }
    if (i < n) off[i] = lds[threadIdx.x] - v;  // exclusive
    if (threadIdx.x == SCAN_B - 1) bsum[blockIdx.x] = lds[threadIdx.x];
}
__global__ void k_scan2(int* __restrict__ bsum, int nb) {
    __shared__ int lds[SCAN_B];
    int v = (threadIdx.x < nb) ? bsum[threadIdx.x] : 0;
    lds[threadIdx.x] = v; __syncthreads();
    for (int s = 1; s < SCAN_B; s <<= 1) {
        int t = (threadIdx.x >= s) ? lds[threadIdx.x - s] : 0;
        __syncthreads();
        lds[threadIdx.x] += t;
        __syncthreads();
    }
    if (threadIdx.x < nb) bsum[threadIdx.x] = lds[threadIdx.x] - v;
}
__global__ void k_scan3(int* __restrict__ off, const int* __restrict__ bsum,
                        int* __restrict__ cursor, int n) {
    int i = blockIdx.x * SCAN_B + threadIdx.x;
    if (i < n) {
        int o = off[i] + bsum[blockIdx.x];
        off[i] = o;
        cursor[i] = o;
    }
}

// ---------------- CSR fill: csr[p] = src | etype<<16 ----------------
__global__ void k_fill(const int* __restrict__ ei, const int* __restrict__ et,
                       int* __restrict__ cursor, unsigned* __restrict__ csr, int E) {
    int e = blockIdx.x * blockDim.x + threadIdx.x;
    if (e < E) {
        int d = ei[E + e];
        int p = atomicAdd(&cursor[d], 1);
        csr[p] = (unsigned)ei[e] | ((unsigned)et[e] << 16);
    }
}

// ---------------- aggregation: Zb[n, b*128+d] = bf16( sum_r comp[r,b]*mean[r,n,d] ) ----
// one node per wave; bf16 input rows (one 256B coalesced load per edge per wave).
__global__ void k_agg(const unsigned short* __restrict__ xb, const int* __restrict__ off,
                      const int* __restrict__ deg, const unsigned* __restrict__ csr,
                      const float* __restrict__ comp, unsigned short* __restrict__ Zb, int Nn) {
    __shared__ float acc[4][R_REL][D];   // 20 KB
    __shared__ float scomp[R_REL * NBASE];
    int w = threadIdx.x >> 6;
    int lane = threadIdx.x & 63;
    if (threadIdx.x < R_REL * NBASE) scomp[threadIdx.x] = comp[threadIdx.x];
    for (int i = threadIdx.x; i < 4 * R_REL * D; i += 256) ((float*)acc)[i] = 0.f;
    __syncthreads();

    int n = blockIdx.x * 4 + w;
    if (n >= Nn) return;

    int start = off[n];
    int dg = deg[n];
    int myCnt = 0;  // lane r holds count of relation r
    float* accw = &acc[w][0][0];
    for (int j = 0; j < dg; ++j) {
        unsigned u = csr[start + j];
        int src = (int)(u & 0xFFFFu);
        int et = (int)(u >> 16);
        unsigned xv = *(const unsigned*)&xb[(size_t)src * D + lane * 2];
        float vx = __uint_as_float(xv << 16);
        float vy = __uint_as_float(xv & 0xFFFF0000u);
        float2 a = *(float2*)&accw[et * D + lane * 2];
        a.x += vx; a.y += vy;
        *(float2*)&accw[et * D + lane * 2] = a;
        if (lane == et) myCnt++;
    }
    float inv[R_REL];
#pragma unroll
    for (int r = 0; r < R_REL; ++r) {
        int c = __shfl(myCnt, r, 64);
        inv[r] = (c > 0) ? (1.f / (float)c) : 1.f;   // max(cnt,1)
    }
    float2 mean[R_REL];
#pragma unroll
    for (int r = 0; r < R_REL; ++r) {
        float2 a = *(float2*)&accw[r * D + lane * 2];
        mean[r].x = a.x * inv[r];
        mean[r].y = a.y * inv[r];
    }
#pragma unroll
    for (int b = 0; b < NBASE; ++b) {
        float zx = 0.f, zy = 0.f;
#pragma unroll
        for (int r = 0; r < R_REL; ++r) {
            float c = scomp[r * NBASE + b];
            zx = fmaf(c, mean[r].x, zx);
            zy = fmaf(c, mean[r].y, zy);
        }
        unsigned o = (unsigned)f2bf(zx) | ((unsigned)f2bf(zy) << 16);
        *(unsigned*)&Zb[(size_t)n * 512 + b * D + lane * 2] = o;
    }
}

// ---------------- B panel transpose+cast: BT[n][k] = bf16([bases;root][k][n]) ----------
__global__ void k_bt(const float* __restrict__ bases, const float* __restrict__ root,
                     unsigned short* __restrict__ BT) {
    int i = blockIdx.x * 256 + threadIdx.x;       // over 128*640
    if (i >= 128 * 640) return;
    int n = i / 640, k = i - n * 640;
    float v = (k < 512) ? bases[(size_t)k * D + n] : root[(size_t)(k - 512) * D + n];
    BT[i] = f2bf(v);
}

// ---------------- MFMA layer GEMM: P = [Zb | xb] @ BT^T + bias ----------------
// M rows, K=640, N=128. BM=32, 256 threads = 4 waves, each wave 16x64.
// LDS rows padded to 80B (5 x 16B slots) -> <=2-way bank aliasing.
__global__ void k_gemm_mfma(const unsigned short* __restrict__ Zb,
                            const unsigned short* __restrict__ xb,
                            const unsigned short* __restrict__ BT,
                            const float* __restrict__ bias,
                            float* __restrict__ P, int M) {
    __shared__ unsigned short As[32 * 40];    // 2.5 KB
    __shared__ unsigned short Bs[128 * 40];   // 10 KB
    int t = threadIdx.x;
    int l = t & 63;
    int w = t >> 6;
    int wm = w & 1;               // m-tile (16 rows)
    int wn = (w >> 1) * 64;       // n-half (64 cols)
    int m0 = blockIdx.x * 32;
    int lrow = l & 15;
    int kq = l >> 4;              // 0..3

    f32x4 acc[4];
#pragma unroll
    for (int ct = 0; ct < 4; ++ct) acc[ct] = (f32x4){0.f, 0.f, 0.f, 0.f};

    // staging assignments (fixed per thread)
    int arow = t >> 3, ako = (t & 7) * 4;         // A: 4 bf16 (8B) each
    int brow = t >> 1, bko = (t & 1) * 16;        // B: 16 bf16 (32B) each, two uint4
    int arg = m0 + arow; if (arg >= M) arg = M - 1;

    const unsigned short* aFrag = &As[(wm * 16 + lrow) * 40 + kq * 8];

    for (int k0 = 0; k0 < 640; k0 += 32) {
        __syncthreads();
        {   // stage A tile [32][32]
            const unsigned short* src = (k0 < 512)
                ? &Zb[(size_t)arg * 512 + k0 + ako]
                : &xb[(size_t)arg * D + (k0 - 512) + ako];
            *(uint2*)&As[arow * 40 + ako] = *(const uint2*)src;
        }
        {   // stage B tile [128][32]: 16 bf16 (32B) per thread = two 16B writes
            const unsigned short* src = &BT[(size_t)brow * 640 + k0 + bko];
            *(uint4*)&Bs[brow * 40 + bko]     = *(const uint4*)src;
            *(uint4*)&Bs[brow * 40 + bko + 8] = *(const uint4*)(src + 8);
        }
        __syncthreads();
        short8 a = *(const short8*)aFrag;
#pragma unroll
        for (int ct = 0; ct < 4; ++ct) {
            short8 b = *(const short8*)&Bs[(wn + ct * 16 + lrow) * 40 + kq * 8];
            acc[ct] = __builtin_amdgcn_mfma_f32_16x16x32_bf16(a, b, acc[ct], 0, 0, 0);
        }
    }

    int r0 = m0 + wm * 16 + kq * 4;
#pragma unroll
    for (int ct = 0; ct < 4; ++ct) {
        int col = wn + ct * 16 + lrow;
        float bv = bias[col];
#pragma unroll
        for (int r = 0; r < 4; ++r) {
            int rg = r0 + r;
            if (rg < M) P[(size_t)rg * D + col] = acc[ct][r] + bv;
        }
    }
}

// ---------------- LayerNorm + ReLU -> bf16 ----------------
__global__ void k_lnrelu(const float* __restrict__ P, const float* __restrict__ g,
                         const float* __restrict__ b, unsigned short* __restrict__ hb, int Nn) {
    int w = threadIdx.x >> 6, lane = threadIdx.x & 63;
    int n = blockIdx.x * 4 + w;
    if (n >= Nn) return;
    float2 v = *(const float2*)&P[(size_t)n * D + lane * 2];
    float s = v.x + v.y;
#pragma unroll
    for (int o = 1; o < 64; o <<= 1) s += __shfl_xor(s, o, 64);
    float m = s * (1.f / 128.f);
    float dx = v.x - m, dy = v.y - m;
    float vs = dx * dx + dy * dy;
#pragma unroll
    for (int o = 1; o < 64; o <<= 1) vs += __shfl_xor(vs, o, 64);
    float inv = rsqrtf(vs * (1.f / 128.f) + LN_EPS);
    float2 gg = *(const float2*)&g[lane * 2];
    float2 bb = *(const float2*)&b[lane * 2];
    float ox = fmaxf(dx * inv * gg.x + bb.x, 0.f);
    float oy = fmaxf(dy * inv * gg.y + bb.y, 0.f);
    unsigned o2 = (unsigned)f2bf(ox) | ((unsigned)f2bf(oy) << 16);
    *(unsigned*)&hb[(size_t)n * D + lane * 2] = o2;
}

// ---------------- final: gather + LN + relu(h@Wc1+bc1) @ Wc2 + bc2 ----------------
__global__ void k_final(const float* __restrict__ P2, const int* __restrict__ nidx,
                        const float* __restrict__ g, const float* __restrict__ b,
                        const float* __restrict__ Wc1, const float* __restrict__ bc1,
                        const float* __restrict__ Wc2, const float* __restrict__ bc2,
                        float* __restrict__ out, int M) {
    __shared__ float ln[D];
    __shared__ float t[D];
    __shared__ float red[2];
    int i = blockIdx.x;
    if (i >= M) return;
    int d = threadIdx.x;
    int n = nidx[i];
    float v = P2[(size_t)n * D + d];
    float s = v;
#pragma unroll
    for (int o = 1; o < 64; o <<= 1) s += __shfl_xor(s, o, 64);
    if ((d & 63) == 0) red[d >> 6] = s;
    __syncthreads();
    float m = (red[0] + red[1]) * (1.f / 128.f);
    __syncthreads();
    float dv = v - m;
    float vs = dv * dv;
#pragma unroll
    for (int o = 1; o < 64; o <<= 1) vs += __shfl_xor(vs, o, 64);
    if ((d & 63) == 0) red[d >> 6] = vs;
    __syncthreads();
    float inv = rsqrtf((red[0] + red[1]) * (1.f / 128.f) + LN_EPS);
    ln[d] = dv * inv * g[d] + b[d];
    __syncthreads();
    float a = bc1[d];
    for (int k = 0; k < D; ++k) a = fmaf(ln[k], Wc1[k * D + d], a);
    t[d] = fmaxf(a, 0.f);
    __syncthreads();
    if (d < NC) {
        float o2 = bc2[d];
        for (int k = 0; k < D; ++k) o2 = fmaf(t[k], Wc2[k * NC + d], o2);
        out[(size_t)i * NC + d] = o2;
    }
}

extern "C" void kernel_launch(void* const* d_in, const int* in_sizes, int n_in,
                              void* d_out, int out_size, void* d_ws, size_t ws_size,
                              hipStream_t stream) {
    const int*   edge_index   = (const int*)d_in[0];
    const int*   edge_type    = (const int*)d_in[1];
    const int*   node_indices = (const int*)d_in[2];
    const float* file_feats   = (const float*)d_in[3];
    const int*   file_idx     = (const int*)d_in[4];
    const float* domain_feats = (const float*)d_in[5];
    const int*   domain_idx   = (const int*)d_in[6];
    const float* ip_feats     = (const float*)d_in[7];
    const int*   ip_idx       = (const int*)d_in[8];
    const float* fallback     = (const float*)d_in[9];
    const float* Wf = (const float*)d_in[10]; const float* bf = (const float*)d_in[11];
    const float* Wd = (const float*)d_in[12]; const float* bd = (const float*)d_in[13];
    const float* Wi = (const float*)d_in[14]; const float* bi = (const float*)d_in[15];
    const float* comp1 = (const float*)d_in[16]; const float* bases1 = (const float*)d_in[17];
    const float* root1 = (const float*)d_in[18]; const float* bias1 = (const float*)d_in[19];
    const float* comp2 = (const float*)d_in[20]; const float* bases2 = (const float*)d_in[21];
    const float* root2 = (const float*)d_in[22]; const float* bias2 = (const float*)d_in[23];
    const float* ln1g = (const float*)d_in[24]; const float* ln1b = (const float*)d_in[25];
    const float* ln2g = (const float*)d_in[26]; const float* ln2b = (const float*)d_in[27];
    const float* Wc1 = (const float*)d_in[28]; const float* bc1 = (const float*)d_in[29];
    const float* Wc2 = (const float*)d_in[30]; const float* bc2 = (const float*)d_in[31];

    const int E  = in_sizes[1];
    const int Nn = in_sizes[9] / D;
    const int Mf = in_sizes[4], Kf = in_sizes[3] / Mf;
    const int Md = in_sizes[6], Kd = in_sizes[5] / Md;
    const int Mi = in_sizes[8], Ki = in_sizes[7] / Mi;
    const int Msel = in_sizes[2];

    char* w = (char*)d_ws;
    auto alloc = [&](size_t bytes) {
        char* p = w;
        w += (bytes + 255) & ~(size_t)255;
        return p;
    };
    unsigned short* xb  = (unsigned short*)alloc((size_t)Nn * D * 2);   // 12.8 MB
    unsigned short* h1b = (unsigned short*)alloc((size_t)Nn * D * 2);   // 12.8 MB
    float*          P   = (float*)alloc((size_t)Nn * D * 4);            // 25.6 MB
    unsigned short* Zb  = (unsigned short*)alloc((size_t)Nn * 512 * 2); // 51.2 MB
    unsigned short* BT1 = (unsigned short*)alloc((size_t)128 * 640 * 2);
    unsigned short* BT2 = (unsigned short*)alloc((size_t)128 * 640 * 2);
    int* deg    = (int*)alloc((size_t)Nn * 4);
    int* off    = (int*)alloc((size_t)Nn * 4);
    int* cursor = (int*)alloc((size_t)Nn * 4);
    int* bsum   = (int*)alloc(1024);
    unsigned* csr = (unsigned*)alloc((size_t)E * 4);                    // 3.2 MB

    hipMemsetAsync(deg, 0, (size_t)Nn * 4, stream);

    // node features (bf16)
    int n4 = Nn * D / 4;
    k_copy_bf<<<(n4 + 255) / 256, 256, 0, stream>>>((const float4*)fallback, (uint2*)xb, n4);
    k_proj8<<<(Mf + 7) / 8, 128, 0, stream>>>(file_feats, Wf, bf, file_idx, xb, Mf, Kf);
    k_proj8<<<(Md + 7) / 8, 128, 0, stream>>>(domain_feats, Wd, bd, domain_idx, xb, Md, Kd);
    k_proj8<<<(Mi + 7) / 8, 128, 0, stream>>>(ip_feats, Wi, bi, ip_idx, xb, Mi, Ki);

    // B panels (bf16, transposed)
    int nbt = (128 * 640 + 255) / 256;
    k_bt<<<nbt, 256, 0, stream>>>(bases1, root1, BT1);
    k_bt<<<nbt, 256, 0, stream>>>(bases2, root2, BT2);

    // CSR by dst (shared by both layers)
    k_deg<<<(E + 255) / 256, 256, 0, stream>>>(edge_index, deg, E);
    int nb = (Nn + SCAN_B - 1) / SCAN_B;
    k_scan1<<<nb, SCAN_B, 0, stream>>>(deg, off, bsum, Nn);
    k_scan2<<<1, SCAN_B, 0, stream>>>(bsum, nb);
    k_scan3<<<nb, SCAN_B, 0, stream>>>(off, bsum, cursor, Nn);
    k_fill<<<(E + 255) / 256, 256, 0, stream>>>(edge_index, edge_type, cursor, csr, E);

    int gemmGrid = (Nn + 31) / 32;

    // layer 1
    k_agg<<<(Nn + 3) / 4, 256, 0, stream>>>(xb, off, deg, csr, comp1, Zb, Nn);
    k_gemm_mfma<<<gemmGrid, 256, 0, stream>>>(Zb, xb, BT1, bias1, P, Nn);
    k_lnrelu<<<(Nn + 3) / 4, 256, 0, stream>>>(P, ln1g, ln1b, h1b, Nn);

    // layer 2
    k_agg<<<(Nn + 3) / 4, 256, 0, stream>>>(h1b, off, deg, csr, comp2, Zb, Nn);
    k_gemm_mfma<<<gemmGrid, 256, 0, stream>>>(Zb, h1b, BT2, bias2, P, Nn);

    // head
    k_final<<<Msel, 128, 0, stream>>>(P, node_indices, ln2g, ln2b, Wc1, bc1, Wc2, bc2,
                                      (float*)d_out, Msel);
}